// Round 6
// baseline (144.630 us; speedup 1.0000x reference)
//
#include <hip/hip_runtime.h>
#include <stdint.h>

// ChamferDistance2D: B=8, N=M=8192, fp32, scalar out.
// R6 = R4 verbatim + ONE change: col-combine covers all NJT*16=512 entries
// (R4's `if (tid < JCH)` with TPB=256 left half of colpart poisoned — the
// exact-1/4 error signature validated everything else in R4).
// d_ij = s_i + S_j - 2 x_i X_j - 2 y_i Y_j via v_mfma_f32_16x16x32_bf16,
// 3-level bf16 split, 18 of 32 K-slots (residual ~2^-24):
//   x*X: hH hM mH hL lH mM (k0-5), y*Y: same (k6-11), s_i*1: k12-14, 1*S_j: k15-17.
// Each unique pair computed ONCE; rows (dir1) and cols (dir2) extracted from C
// (col=lane&15, row=quad*4+reg). Col mins via LDS atomicMin on clamped float
// bits; row mins via shfl_xor over the 16-lane n-group.
// ws: atab 4MB @0, btab 4MB @4M, rowpart 4MB @8M, colpart 8MB @12M.

#define BATCH 8
#define NPTS  8192
#define TPB   256
#define NTILES 512            // 16-point tiles per batch
#define NICHUNK 32            // i-chunks of 256 points
#define NJSPLIT 16            // j-splits of 512 points
#define JCH   512
#define NJT   32              // 16-wide j-tiles per block

typedef short bf16x8 __attribute__((ext_vector_type(8)));
typedef float f32x4  __attribute__((ext_vector_type(4)));

__device__ inline float min3f(float a, float b, float c) {
    float d;
    asm("v_min3_f32 %0, %1, %2, %3" : "=v"(d) : "v"(a), "v"(b), "v"(c));
    return d;
}

__device__ inline uint32_t bf_rtn_u(float v) {   // fp32 -> bf16 bits, RTN-even
    uint32_t u = __float_as_uint(v);
    return (u + 0x7FFFu + ((u >> 16) & 1u)) >> 16;
}
__device__ inline void split3(float v, uint32_t& h, uint32_t& m, uint32_t& l) {
    h = bf_rtn_u(v);
    float r1 = v - __uint_as_float(h << 16);   // exact (Sterbenz)
    m = bf_rtn_u(r1);
    float r2 = r1 - __uint_as_float(m << 16);  // exact
    l = bf_rtn_u(r2);                          // residual <= 2^-24 |v|
}

// grid = 2*BATCH*NTILES*64/TPB = 2048. Builds per-lane MFMA fragment records.
// A layout: A[m=lane&15][k=q*8+j]; B layout: B[k=q*8+j][n=lane&15].
__global__ void chamfer_prep(const float* __restrict__ p1, const float* __restrict__ p2,
                             uint4* __restrict__ atab, uint4* __restrict__ btab,
                             float* __restrict__ out) {
    int g = blockIdx.x * TPB + threadIdx.x;
    if (g == 0) *out = 0.0f;                   // zero scalar output (pre-reduce)
    int lane = g & 63;
    int tile = (g >> 6) & (NTILES - 1);
    int b    = (g >> 15) & (BATCH - 1);
    int tb   = g >> 18;                        // 0: A-side (p1), 1: B-side (p2)
    int m = lane & 15, q = lane >> 4;

    const float2* src = (const float2*)(tb ? p2 : p1);
    float2 P = src[(size_t)b * NPTS + tile * 16 + m];
    float s = fmaf(P.x, P.x, P.y * P.y);
    float x = tb ? -2.0f * P.x : P.x;          // exact -2 scale on B side
    float y = tb ? -2.0f * P.y : P.y;

    uint32_t xh, xm, xl, yh, ym, yl, sh, sm, sl;
    split3(x, xh, xm, xl);
    split3(y, yh, ym, yl);
    split3(s, sh, sm, sl);
    const uint32_t ONE = 0x3F80u;

    // K-slot table (k: a_i * b_j):
    //  0:xh*Xh 1:xh*Xm 2:xm*Xh 3:xh*Xl 4:xl*Xh 5:xm*Xm
    //  6:yh*Yh 7:yh*Ym 8:ym*Yh 9:yh*Yl 10:yl*Yh 11:ym*Ym
    //  12..14: s_i*1   15..17: 1*S_j   18..31: 0
    uint32_t e[8] = {0,0,0,0,0,0,0,0};
    if (tb == 0) {
        if (q == 0)      { e[0]=xh;e[1]=xh;e[2]=xm;e[3]=xh;e[4]=xl;e[5]=xm;e[6]=yh;e[7]=yh; }
        else if (q == 1) { e[0]=ym;e[1]=yh;e[2]=yl;e[3]=ym;e[4]=sh;e[5]=sm;e[6]=sl;e[7]=ONE; }
        else if (q == 2) { e[0]=ONE;e[1]=ONE; }
    } else {
        if (q == 0)      { e[0]=xh;e[1]=xm;e[2]=xh;e[3]=xl;e[4]=xh;e[5]=xm;e[6]=yh;e[7]=ym; }
        else if (q == 1) { e[0]=yh;e[1]=yl;e[2]=yh;e[3]=ym;e[4]=ONE;e[5]=ONE;e[6]=ONE;e[7]=sh; }
        else if (q == 2) { e[0]=sm;e[1]=sl; }
    }
    uint4 w;
    w.x = (e[1] << 16) | e[0];
    w.y = (e[3] << 16) | e[2];
    w.z = (e[5] << 16) | e[4];
    w.w = (e[7] << 16) | e[6];
    (tb ? btab : atab)[((size_t)b * NTILES + tile) * 64 + lane] = w;
}

// grid = BATCH * NICHUNK * NJSPLIT = 4096. Block: 256 i's x 512 j's.
__global__ __launch_bounds__(TPB, 3)
void chamfer_partial(const uint4* __restrict__ atab, const uint4* __restrict__ btab,
                     float* __restrict__ rowpart /* [B][NJSPLIT][NPTS] */,
                     float* __restrict__ colpart /* [B][NICHUNK][NPTS] */) {
    __shared__ uint4 ldsB[NJT * 64];          // 32 KB B-fragments
    __shared__ unsigned int colbuf[NJT * 64]; // 8 KB per-(jt,quad,n) col mins
    __shared__ float rowbuf[TPB];             // 1 KB row-min transpose

    int bx = blockIdx.x;
    int jsplit = bx & (NJSPLIT - 1);
    int ichunk = (bx >> 4) & (NICHUNK - 1);
    int b      = bx >> 9;

    int tid  = threadIdx.x;
    int lane = tid & 63;
    int w    = tid >> 6;

    const uint4* bsrc = btab + ((size_t)b * NTILES + jsplit * NJT) * 64;
    for (int idx = tid; idx < NJT * 64; idx += TPB) ldsB[idx] = bsrc[idx];
    for (int idx = tid; idx < NJT * 64; idx += TPB) colbuf[idx] = 0x7F800000u;

    // wave's 4 A-fragments (i-tiles ichunk*16 + w*4 + it)
    const uint4* asrc = atab + ((size_t)b * NTILES + ichunk * 16 + w * 4) * 64 + lane;
    uint4 atmp[4];
#pragma unroll
    for (int it = 0; it < 4; ++it) atmp[it] = asrc[it * 64];

    f32x4 zeroc = {0.0f, 0.0f, 0.0f, 0.0f};
    float accr[16];
#pragma unroll
    for (int i2 = 0; i2 < 16; ++i2) accr[i2] = 3.0e38f;

    __syncthreads();

    for (int jt = 0; jt < NJT; ++jt) {
        bf16x8 bf = *(const bf16x8*)&ldsB[jt * 64 + lane];
        float accc = 3.0e38f;
#pragma unroll
        for (int it = 0; it < 4; ++it) {
            bf16x8 af = *(const bf16x8*)&atmp[it];
            f32x4 C = __builtin_amdgcn_mfma_f32_16x16x32_bf16(af, bf, zeroc, 0, 0, 0);
            // rows: lane holds col n=lane&15, rows q*4+r of this i-tile
            accr[it * 4 + 0] = fminf(accr[it * 4 + 0], C[0]);
            accr[it * 4 + 1] = fminf(accr[it * 4 + 1], C[1]);
            accr[it * 4 + 2] = fminf(accr[it * 4 + 2], C[2]);
            accr[it * 4 + 3] = fminf(accr[it * 4 + 3], C[3]);
            accc = min3f(min3f(accc, C[0], C[1]), C[2], C[3]);
        }
        // col min across waves: d >= 0 so clamped float bits order as uints
        atomicMin(&colbuf[jt * 64 + lane], __float_as_uint(fmaxf(accc, 0.0f)));
    }

    // row mins: reduce across the 16-lane n-group (xor 1,2,4,8 stays in-group)
#pragma unroll
    for (int i2 = 0; i2 < 16; ++i2) {
        float v = accr[i2];
        v = fminf(v, __shfl_xor(v, 1, 64));
        v = fminf(v, __shfl_xor(v, 2, 64));
        v = fminf(v, __shfl_xor(v, 4, 64));
        v = fminf(v, __shfl_xor(v, 8, 64));
        accr[i2] = v;
    }
    __syncthreads();   // all colbuf atomics done

    if ((lane & 15) == 0) {
        int q = lane >> 4;
#pragma unroll
        for (int it = 0; it < 4; ++it)
#pragma unroll
            for (int r = 0; r < 4; ++r)
                rowbuf[w * 64 + it * 16 + q * 4 + r] = accr[it * 4 + r];
    }
    // col final: combine 4 quads per (jt, n) — R6 FIX: strided loop covers all
    // 512 entries (R4's `if (tid < JCH)` only covered 256 of them)
    for (int idx = tid; idx < NJT * 16; idx += TPB) {
        int jt = idx >> 4, n = idx & 15;
        unsigned int v0 = colbuf[jt * 64 + n];
        unsigned int v1 = colbuf[jt * 64 + 16 + n];
        unsigned int v2 = colbuf[jt * 64 + 32 + n];
        unsigned int v3 = colbuf[jt * 64 + 48 + n];
        unsigned int mn = min(min(v0, v1), min(v2, v3));
        colpart[((size_t)b * NICHUNK + ichunk) * NPTS + jsplit * JCH + idx] = __uint_as_float(mn);
    }
    __syncthreads();
    rowpart[((size_t)b * NJSPLIT + jsplit) * NPTS + ichunk * 256 + tid] = rowbuf[tid];
}

// grid = 2*BATCH*NPTS/TPB = 512
__global__ __launch_bounds__(TPB)
void chamfer_reduce(const float* __restrict__ rowpart, const float* __restrict__ colpart,
                    float* __restrict__ out) {
    int gid  = blockIdx.x * TPB + threadIdx.x;
    int pt   = gid & (NPTS - 1);
    int b    = (gid >> 13) & (BATCH - 1);
    int side = gid >> 16;

    float m;
    if (side == 0) {
        const float* base = rowpart + (size_t)b * NJSPLIT * NPTS + pt;
        m = base[0];
#pragma unroll
        for (int s = 1; s < NJSPLIT; ++s) m = fminf(m, base[(size_t)s * NPTS]);
    } else {
        const float* base = colpart + (size_t)b * NICHUNK * NPTS + pt;
        m = base[0];
#pragma unroll
        for (int s = 1; s < NICHUNK; ++s) m = fminf(m, base[(size_t)s * NPTS]);
    }

    float d = m;
#pragma unroll
    for (int off = 32; off > 0; off >>= 1)
        d += __shfl_down(d, off, 64);

    __shared__ float wsum[TPB / 64];
    int lane = threadIdx.x & 63;
    int wv   = threadIdx.x >> 6;
    if (lane == 0) wsum[wv] = d;
    __syncthreads();
    if (threadIdx.x == 0) {
        float ssum = wsum[0] + wsum[1] + wsum[2] + wsum[3];
        atomicAdd(out, ssum * (1.0f / NPTS));
    }
}

extern "C" void kernel_launch(void* const* d_in, const int* in_sizes, int n_in,
                              void* d_out, int out_size, void* d_ws, size_t ws_size,
                              hipStream_t stream) {
    const float* p1 = (const float*)d_in[0];
    const float* p2 = (const float*)d_in[1];
    float* out = (float*)d_out;

    char* ws = (char*)d_ws;
    uint4* atab    = (uint4*)(ws);
    uint4* btab    = (uint4*)(ws + (size_t)4 * 1024 * 1024);
    float* rowpart = (float*)(ws + (size_t)8 * 1024 * 1024);
    float* colpart = (float*)(ws + (size_t)12 * 1024 * 1024);
    // requires 20 MB workspace (>=33.5 MB proven available in R2)

    chamfer_prep<<<2048, TPB, 0, stream>>>(p1, p2, atab, btab, out);
    chamfer_partial<<<BATCH * NICHUNK * NJSPLIT, TPB, 0, stream>>>(atab, btab, rowpart, colpart);
    chamfer_reduce<<<2 * BATCH * NPTS / TPB, TPB, 0, stream>>>(rowpart, colpart, out);
}

// Round 8
// 124.624 us; speedup vs baseline: 1.1605x; 1.1605x over previous
//
#include <hip/hip_runtime.h>

// ChamferDistance2D: B=8, N=M=8192, fp32, scalar output.
// cost = sum_b [ mean_i min_j d(i,j) + mean_j min_i d(i,j) ],  d = squared L2.
// d(i,j) = |p1_i|^2 + (|p2_j|^2 - 2 p1_i . p2_j); store min_j of the paren term.
//
// R8 = R3 (green, 68us partial) minus its measured fat: the 4-j software
// pipeline's rotation movs (16 v_mov per 40 math ops). Inner loop is now
// unroll-8 reading q[] directly — 8 ds_read_b128 + 320 math VALU per group;
// LDS latency hidden by 16 waves/CU (4 blocks/CU, grid 1024 = exactly 4x256).
// Per pair-dir: 2 v_fma_f32 + 0.5 v_min3_f32 = 2.5 lane-ops (static floor 34us).
// MFMA formulation abandoned: green version (R6) measured SLOWER than scalar
// (86 vs 68us, hidden AGPR-shuttle VALU), restructured versions failed
// correctness twice for reasons invisible without disasm.

#define BATCH 8
#define NPTS  8192
#define TPB   256
#define IPT   16
#define PPB   (TPB * IPT)     // 4096
#define TILES (NPTS / PPB)    // 2
#define S     32              // j-splits
#define JCH   (NPTS / S)      // 256 j's per block

__device__ inline float min3f(float a, float b, float c) {
    float d;
    asm("v_min3_f32 %0, %1, %2, %3" : "=v"(d) : "v"(a), "v"(b), "v"(c));
    return d;
}

// grid.x = 2 * BATCH * TILES * S = 1024
__global__ __launch_bounds__(TPB, 4)
void chamfer_partial(const float* __restrict__ p1, const float* __restrict__ p2,
                     float* __restrict__ partial /* [2][B][S][N] */,
                     float* __restrict__ out_to_zero) {
    __shared__ float4 q[JCH];      // (x, y, |p|^2, pad)

    if (blockIdx.x == 0 && threadIdx.x == 0) *out_to_zero = 0.0f;

    int blk   = blockIdx.x;
    int split = blk & (S - 1);      blk >>= 5;
    int tile  = blk & (TILES - 1);  blk >>= 1;
    int b     = blk & (BATCH - 1);  blk >>= 3;
    int dir   = blk;

    const float2* a  = (const float2*)(dir ? p2 : p1) + (size_t)b * NPTS;
    const float2* bp = (const float2*)(dir ? p1 : p2) + (size_t)b * NPTS + split * JCH;

    int t = threadIdx.x;

    for (int j = t; j < JCH; j += TPB) {
        float2 v = bp[j];
        q[j] = make_float4(v.x, v.y, fmaf(v.x, v.x, v.y * v.y), 0.0f);
    }

    int pt_base = tile * PPB;
    float xp[IPT], yp[IPT], m[IPT];
#pragma unroll
    for (int k = 0; k < IPT; ++k) {
        float2 v = a[pt_base + k * TPB + t];
        xp[k] = -2.0f * v.x;
        yp[k] = -2.0f * v.y;
        m[k]  = 3.0e38f;
    }

    __syncthreads();

    // unroll-8, direct q[] reads: no rotation movs; broadcast ds_read_b128 x8
    // per group feeds 16x8 = 128 pairs of math (LDS pipe ~hidden).
    for (int j = 0; j < JCH; j += 8) {
        float4 q0 = q[j + 0], q1 = q[j + 1], q2 = q[j + 2], q3 = q[j + 3];
        float4 q4 = q[j + 4], q5 = q[j + 5], q6 = q[j + 6], q7 = q[j + 7];
#pragma unroll
        for (int k = 0; k < IPT; ++k) {
            float t0 = fmaf(yp[k], q0.y, fmaf(xp[k], q0.x, q0.z));
            float t1 = fmaf(yp[k], q1.y, fmaf(xp[k], q1.x, q1.z));
            float t2 = fmaf(yp[k], q2.y, fmaf(xp[k], q2.x, q2.z));
            float t3 = fmaf(yp[k], q3.y, fmaf(xp[k], q3.x, q3.z));
            float t4 = fmaf(yp[k], q4.y, fmaf(xp[k], q4.x, q4.z));
            float t5 = fmaf(yp[k], q5.y, fmaf(xp[k], q5.x, q5.z));
            float t6 = fmaf(yp[k], q6.y, fmaf(xp[k], q6.x, q6.z));
            float t7 = fmaf(yp[k], q7.y, fmaf(xp[k], q7.x, q7.z));
            m[k] = min3f(m[k], t0, t1);
            m[k] = min3f(m[k], t2, t3);
            m[k] = min3f(m[k], t4, t5);
            m[k] = min3f(m[k], t6, t7);
        }
    }

    float* outp = partial + ((size_t)((dir * BATCH + b) * S + split)) * NPTS + pt_base;
#pragma unroll
    for (int k = 0; k < IPT; ++k)
        outp[k * TPB + t] = m[k];
}

// grid.x = 2 * BATCH * NPTS / TPB = 512
__global__ __launch_bounds__(TPB)
void chamfer_reduce(const float* __restrict__ p1, const float* __restrict__ p2,
                    const float* __restrict__ partial, float* __restrict__ out) {
    int gid   = blockIdx.x * TPB + threadIdx.x;
    int point = gid & (NPTS - 1);
    int rest  = gid >> 13;
    int b     = rest & (BATCH - 1);
    int dir   = rest >> 3;

    const float* base = partial + ((size_t)(dir * BATCH + b) * S) * NPTS + point;
    float m = base[0];
#pragma unroll
    for (int s = 1; s < S; ++s)
        m = fminf(m, base[(size_t)s * NPTS]);

    float2 v = ((const float2*)(dir ? p2 : p1))[(size_t)b * NPTS + point];
    float d = m + fmaf(v.x, v.x, v.y * v.y);

#pragma unroll
    for (int off = 32; off > 0; off >>= 1)
        d += __shfl_down(d, off, 64);

    __shared__ float wsum[TPB / 64];
    int lane = threadIdx.x & 63;
    int w    = threadIdx.x >> 6;
    if (lane == 0) wsum[w] = d;
    __syncthreads();
    if (threadIdx.x == 0) {
        float ssum = wsum[0] + wsum[1] + wsum[2] + wsum[3];
        atomicAdd(out, ssum * (1.0f / NPTS));
    }
}

extern "C" void kernel_launch(void* const* d_in, const int* in_sizes, int n_in,
                              void* d_out, int out_size, void* d_ws, size_t ws_size,
                              hipStream_t stream) {
    const float* p1 = (const float*)d_in[0];
    const float* p2 = (const float*)d_in[1];
    float* out      = (float*)d_out;
    float* partial  = (float*)d_ws;   // needs 2*8*32*8192*4 = 16 MB (32 MB proven in R2)

    chamfer_partial<<<2 * BATCH * TILES * S, TPB, 0, stream>>>(p1, p2, partial, out);
    chamfer_reduce<<<2 * BATCH * NPTS / TPB, TPB, 0, stream>>>(p1, p2, partial, out);
}